// Round 1
// baseline (98.140 us; speedup 1.0000x reference)
//
#include <hip/hip_runtime.h>

// CustomEmbedding: out[b,s,:] = (x<1000) ? powers(softsign((x-mean)/std)) : W[x]
// x: [32,4096] int32, W: [50257,512] f32, out: [32,4096,512] f32.
// Memory-bound: 268 MB out-write + gather reads of W (103 MB, L3-resident).

#define DIMV 128          // 512 floats / 4 per thread = 128 threads per token
#define NUM_COUNT 1000

// mean = 499.5 ; std = sqrt(83333.25) + 1e-6 = 288.67499125725 (float64-derived)
__global__ __launch_bounds__(256) void custom_embedding_kernel(
    const int* __restrict__ x, const float* __restrict__ W,
    float* __restrict__ out, int n_tokens) {
    int gid = blockIdx.x * blockDim.x + threadIdx.x;   // one float4 per thread
    int token = gid >> 7;       // /128
    int lane  = gid & 127;
    if (token >= n_tokens) return;

    int id = x[token];
    float4 v;
    if (id < NUM_COUNT) {
        const float kMean = 499.5f;
        const float kInvStd = 1.0f / 288.67499125725f;
        float n = ((float)id - kMean) * kInvStd;
        float s = n / (1.0f + fabsf(n));               // softsign, |s| <= 0.634
        float a = fabsf(s);
        float l = log2f(a);
        int e0 = (lane << 2) + 1;                      // exponent of first element (odd)
        float m = exp2f((float)e0 * l);                // |s|^e0
        float p0 = (s < 0.0f) ? -m : m;                // e0 odd -> sign(s) applies
        float p1 = p0 * s;
        float p2 = p1 * s;
        float p3 = p2 * s;
        v = make_float4(p0, p1, p2, p3);
    } else {
        v = reinterpret_cast<const float4*>(W)[(size_t)id * DIMV + lane];
    }
    reinterpret_cast<float4*>(out)[gid] = v;
}

extern "C" void kernel_launch(void* const* d_in, const int* in_sizes, int n_in,
                              void* d_out, int out_size, void* d_ws, size_t ws_size,
                              hipStream_t stream) {
    const int*   x = (const int*)d_in[0];
    const float* W = (const float*)d_in[1];
    float*     out = (float*)d_out;
    int n_tokens = in_sizes[0];                        // 32*4096 = 131072

    long long total_threads = (long long)n_tokens * DIMV;
    int block = 256;
    int grid = (int)((total_threads + block - 1) / block);
    custom_embedding_kernel<<<grid, block, 0, stream>>>(x, W, out, n_tokens);
}

// Round 3
// 82.078 us; speedup vs baseline: 1.1957x; 1.1957x over previous
//
#include <hip/hip_runtime.h>

// CustomEmbedding: out[b,s,:] = (x<1000) ? powers(softsign((x-mean)/std)) : W[x]
// x: [32,4096] int32, W: [50257,512] f32, out: [32,4096,512] f32 (268 MB).
// Memory/latency-bound. Design: 4 tokens per thread -> 4 independent W-row
// gathers in flight (hides L2/L3 hit latency); gathers issued unconditionally
// (num-token branch only overwrites, ~2% of tokens); nontemporal stores keep
// the 268 MB write-only stream from thrashing L2 entries holding hot W rows.

#define NUM_COUNT 1000
#define TOK_PER_THREAD 4

typedef float f32x4 __attribute__((ext_vector_type(4)));   // native clang vector
typedef int   i32x4 __attribute__((ext_vector_type(4)));

__device__ __forceinline__ f32x4 num_powers(int id, int lane) {
    // mean = 499.5 ; std = sqrt(83333.25) + 1e-6
    const float kMean = 499.5f;
    const float kInvStd = 1.0f / 288.67499125725f;
    float n = ((float)id - kMean) * kInvStd;
    float s = n / (1.0f + fabsf(n));                   // softsign, |s| <= 0.634
    float a = fabsf(s);
    float l = log2f(a);
    int e0 = (lane << 2) + 1;                          // first exponent (odd)
    float m = exp2f((float)e0 * l);                    // |s|^e0
    float p0 = (s < 0.0f) ? -m : m;                    // e0 odd -> sign(s)
    float p1 = p0 * s;
    float p2 = p1 * s;
    float p3 = p2 * s;
    f32x4 r = {p0, p1, p2, p3};
    return r;
}

__global__ __launch_bounds__(256) void custom_embedding_kernel(
    const int* __restrict__ x, const float* __restrict__ W,
    float* __restrict__ out, int n_groups) {
    int gid = blockIdx.x * blockDim.x + threadIdx.x;
    int g    = gid >> 7;        // token-group (4 tokens), 128 lanes each
    int lane = gid & 127;
    if (g >= n_groups) return;

    i32x4 ids = *reinterpret_cast<const i32x4*>(&x[g * 4]);  // tokens 4g..4g+3

    const f32x4* Wv = reinterpret_cast<const f32x4*>(W);
    // 4 independent gathers in flight before any use
    f32x4 v0 = Wv[(size_t)ids.x * 128 + lane];
    f32x4 v1 = Wv[(size_t)ids.y * 128 + lane];
    f32x4 v2 = Wv[(size_t)ids.z * 128 + lane];
    f32x4 v3 = Wv[(size_t)ids.w * 128 + lane];

    // rare (~2%) wave-uniform overwrites for numeric tokens
    if (ids.x < NUM_COUNT) v0 = num_powers(ids.x, lane);
    if (ids.y < NUM_COUNT) v1 = num_powers(ids.y, lane);
    if (ids.z < NUM_COUNT) v2 = num_powers(ids.z, lane);
    if (ids.w < NUM_COUNT) v3 = num_powers(ids.w, lane);

    f32x4* outv = reinterpret_cast<f32x4*>(out);
    size_t base = (size_t)g * (TOK_PER_THREAD * 128) + lane;
    __builtin_nontemporal_store(v0, &outv[base]);
    __builtin_nontemporal_store(v1, &outv[base + 128]);
    __builtin_nontemporal_store(v2, &outv[base + 256]);
    __builtin_nontemporal_store(v3, &outv[base + 384]);
}

extern "C" void kernel_launch(void* const* d_in, const int* in_sizes, int n_in,
                              void* d_out, int out_size, void* d_ws, size_t ws_size,
                              hipStream_t stream) {
    const int*   x = (const int*)d_in[0];
    const float* W = (const float*)d_in[1];
    float*     out = (float*)d_out;
    int n_tokens = in_sizes[0];                        // 131072
    int n_groups = n_tokens / TOK_PER_THREAD;          // 32768 (divisible)

    long long total_threads = (long long)n_groups * 128;
    int block = 256;
    int grid = (int)((total_threads + block - 1) / block);
    custom_embedding_kernel<<<grid, block, 0, stream>>>(x, W, out, n_groups);
}